// Round 3
// baseline (367.381 us; speedup 1.0000x reference)
//
#include <hip/hip_runtime.h>
#include <hip/hip_bf16.h>

// CSPN 3x3 propagation, all-float32 (confirmed: round-2 bf16 reinterpretation
// of the buffers produced NaN — low halfwords of f32 hit NaN bf16 patterns —
// and the 0.4625 threshold is exactly 2% of max|ref|=23.125, a generic
// relative threshold, not bf16 evidence).
//
//   out[b,y,x] = sum_{t=0..8, t=dy*3+dx} k[b,t,y,x] * patch(t)
//   patch(t) = zero-padded input at (y+dy-1, x+dx-1), EXCEPT t==4 (center),
//   which is input0[b,y,x].
//
// ROUND-1 BUG FIXED HERE: input0 must feed ONLY tap 4. Taps 3 and 5 read the
// original input row at overlapping x — keep row[1] pristine and use a
// separate c0 vector for the center tap.
//
// Memory-bound: 48 B/px (36 B kernel + 4 B in + 4 B in0 + 4 B out) ~= 329 MB
// total -> ~52 us at 6.3 TB/s. One thread = 4 consecutive x (aligned float4).

#define BS 16
#define H  352
#define W  1216
#define HW (H * W)
#define WQ (W / 4)   // 304

__global__ __launch_bounds__(256) void cspn_kernel(
    const float* __restrict__ ker,   // [BS, 9, H, W]
    const float* __restrict__ inp,   // [BS, 1, H, W]
    const float* __restrict__ inp0,  // [BS, 1, H, W]
    float* __restrict__ out)         // [BS, 1, H, W]
{
    int tid = blockIdx.x * blockDim.x + threadIdx.x;
    const int total = BS * H * WQ;
    if (tid >= total) return;

    int xq = tid % WQ;
    int t  = tid / WQ;
    int y  = t % H;
    int b  = t / H;
    int x0 = xq * 4;

    // Gather 3 input rows, 6 columns each: input[y+dy-1][x0-1 .. x0+4].
    // NEVER overwritten — taps 3 and 5 need the original center row.
    float row[3][6];
    const float* inb = inp + (size_t)b * HW;
#pragma unroll
    for (int dy = 0; dy < 3; ++dy) {
        int yy = y + dy - 1;
        if (yy < 0 || yy >= H) {
#pragma unroll
            for (int c = 0; c < 6; ++c) row[dy][c] = 0.f;
        } else {
            const float* r = inb + (size_t)yy * W + x0;
            float4 v = *(const float4*)r;
            row[dy][1] = v.x; row[dy][2] = v.y;
            row[dy][3] = v.z; row[dy][4] = v.w;
            row[dy][0] = (x0 > 0)     ? r[-1] : 0.f;
            row[dy][5] = (x0 + 4 < W) ? r[4]  : 0.f;
        }
    }

    // Center tap values (tap 4 ONLY) come from input0.
    float4 c0 = *(const float4*)(inp0 + (size_t)b * HW + (size_t)y * W + x0);
    float cen[4] = {c0.x, c0.y, c0.z, c0.w};

    float acc[4] = {0.f, 0.f, 0.f, 0.f};
    const float* kb = ker + (size_t)b * 9 * HW + (size_t)y * W + x0;
#pragma unroll
    for (int t9 = 0; t9 < 9; ++t9) {
        int dy = t9 / 3, dx = t9 % 3;
        float4 kv = *(const float4*)(kb + (size_t)t9 * HW);
        float kf[4] = {kv.x, kv.y, kv.z, kv.w};
#pragma unroll
        for (int l = 0; l < 4; ++l) {
            float p = (t9 == 4) ? cen[l] : row[dy][dx + l];
            acc[l] = fmaf(kf[l], p, acc[l]);
        }
    }

    float4 o = make_float4(acc[0], acc[1], acc[2], acc[3]);
    *(float4*)(out + (size_t)b * HW + (size_t)y * W + x0) = o;
}

extern "C" void kernel_launch(void* const* d_in, const int* in_sizes, int n_in,
                              void* d_out, int out_size, void* d_ws, size_t ws_size,
                              hipStream_t stream) {
    // Kernel tensor is the 9x-sized buffer; remaining two keep dict order:
    // input, then input0.
    int ki = 0;
    for (int i = 1; i < n_in; ++i)
        if (in_sizes[i] > in_sizes[ki]) ki = i;
    int rest[2], nr = 0;
    for (int i = 0; i < n_in; ++i)
        if (i != ki) rest[nr++] = i;

    const float* ker  = (const float*)d_in[ki];
    const float* inp  = (const float*)d_in[rest[0]];
    const float* inp0 = (const float*)d_in[rest[1]];
    float* out = (float*)d_out;

    const int total = BS * H * WQ;           // threads, 4 px each
    const int block = 256;
    const int grid  = (total + block - 1) / block;
    cspn_kernel<<<grid, block, 0, stream>>>(ker, inp, inp0, out);
}